// Round 16
// baseline (320.448 us; speedup 1.0000x reference)
//
#include <hip/hip_runtime.h>

typedef unsigned short u16;
typedef short bf16x8 __attribute__((ext_vector_type(8)));
typedef float f32x4 __attribute__((ext_vector_type(4)));

__device__ __forceinline__ u16 f2bf(float f) {
  union { float f; unsigned u; } x; x.f = f;
  unsigned r = x.u + 0x7FFFu + ((x.u >> 16) & 1u);
  return (u16)(r >> 16);
}
__device__ __forceinline__ float gelu_f(float x) {
  float t = 0.7978845608028654f * x * (1.f + 0.044715f * x * x);
  return x / (1.f + __expf(-2.f * t));
}
// async global->LDS, 16B/lane; LDS dest linear (wave-uniform base + lane*16)
__device__ __forceinline__ void gll16(const void* g, void* l) {
  __builtin_amdgcn_global_load_lds(
      (const __attribute__((address_space(1))) unsigned int*)g,
      (__attribute__((address_space(3))) unsigned int*)l, 16, 0, 0);
}
// token row -> image offset (shifted window map; same for read & reverse)
__device__ __forceinline__ size_t winmap(int t) {
  int win = t / 49, i = t - win * 49;
  int b = win >> 6, wi = win & 63;
  int ih = i / 7, iw = i - ih * 7;
  int h2 = (wi >> 3) * 7 + ih + 3; if (h2 >= 56) h2 -= 56;
  int w2 = (wi & 7) * 7 + iw + 3; if (w2 >= 56) w2 -= 56;
  return ((size_t)b * 3136 + (size_t)h2 * 56 + w2) * 256;
}

// ---------------- merged weight prep: 6 LDS-tile transposes + bias_prep -----
__global__ __launch_bounds__(256)
void prep_all(const float* __restrict__ wq, const float* __restrict__ wk,
              const float* __restrict__ wv, const float* __restrict__ wp,
              const float* __restrict__ fw1, const float* __restrict__ fw2,
              u16* __restrict__ wqt, u16* __restrict__ wkt,
              u16* __restrict__ wvt, u16* __restrict__ wpt,
              u16* __restrict__ fw1t, u16* __restrict__ fw2t,
              const float* __restrict__ rel, const float* __restrict__ mask,
              float* __restrict__ Bp) {
  const int bx = blockIdx.x;
  const int tid = threadIdx.x;
  if (bx >= 192) {  // ---- bias_prep ----
    const int blk = bx - 192;  // 0..511
    const int wi = blk >> 3, h = blk & 7;
    const float* mrow = mask + (size_t)wi * 2401;
    float* ob = Bp + (size_t)blk * 4096;
#pragma unroll
    for (int e = 0; e < 16; ++e) {
      int pos = e * 256 + tid;
      int r = pos & 3, lane = (pos >> 2) & 63, mini = pos >> 8;
      int mi = mini >> 2, ni = mini & 3;
      int row = mi * 16 + (lane >> 4) * 4 + r;
      int col = ni * 16 + (lane & 15);
      float val;
      if (col >= 49) val = -1e30f;
      else if (row >= 49) val = 0.f;
      else {
        int idx = (row / 7 - col / 7 + 6) * 13 + (row % 7 - col % 7 + 6);
        val = rel[idx * 8 + h] + mrow[row * 49 + col];
      }
      ob[pos] = val;
    }
    return;
  }
  // ---- transpose tile: out[n*K+k] = bf16(in[k*N+n]) ----
  const float* in; u16* out; int K, N, t;
  if (bx < 64) {
    int j = bx >> 4; t = bx & 15; K = 256; N = 256;
    in = j == 0 ? wq : (j == 1 ? wk : (j == 2 ? wv : wp));
    out = j == 0 ? wqt : (j == 1 ? wkt : (j == 2 ? wvt : wpt));
  } else if (bx < 128) {
    t = bx - 64; in = fw1; out = fw1t; K = 256; N = 1024;
  } else {
    t = bx - 128; in = fw2; out = fw2t; K = 1024; N = 256;
  }
  const int ntn = N >> 6;
  const int tk = t / ntn, tn = t - tk * ntn;
  __shared__ u16 tile[64][72];
#pragma unroll
  for (int it = 0; it < 4; ++it) {
    int G = it * 256 + tid;
    int kk = G >> 4, gg = G & 15;
    float4 v = *(const float4*)(in + (size_t)(tk * 64 + kk) * N + tn * 64 + gg * 4);
    tile[kk][gg * 4 + 0] = f2bf(v.x);
    tile[kk][gg * 4 + 1] = f2bf(v.y);
    tile[kk][gg * 4 + 2] = f2bf(v.z);
    tile[kk][gg * 4 + 3] = f2bf(v.w);
  }
  __syncthreads();
#pragma unroll
  for (int it = 0; it < 4; ++it) {
    int G = it * 256 + tid;
    int nn = G >> 4, gk = G & 15;
    ushort4 o;
    o.x = tile[gk * 4 + 0][nn];
    o.y = tile[gk * 4 + 1][nn];
    o.z = tile[gk * 4 + 2][nn];
    o.w = tile[gk * 4 + 3][nn];
    *(ushort4*)(out + (size_t)(tn * 64 + nn) * K + tk * 64 + gk * 4) = o;
  }
}

// ---------------------------------------------------- K=256 GEMM, A-in-regs -
// BM=64/block, 4 waves as 2M x 2N; B in 32-col LDS chunks (32KB dbuf).
// QKV=1: LN1 + cyclic-shift + window-partition fused in-LDS (A from fp32 x),
//        y batches the 3 matrices; alpha applies to Q only.
// QKV=0/EPI=2: proj; A = bf16 attn_o; fp32 scatter win_rev + residual.
template <int EPI, int QKV>
__global__ __launch_bounds__(256, 4)
void gemm_k256(const float* __restrict__ X0, const float* __restrict__ X1,
               const float* __restrict__ X2, const float* __restrict__ lng,
               const float* __restrict__ lnb, const u16* __restrict__ Abf,
               const u16* __restrict__ Bt, const float* __restrict__ b0,
               const float* __restrict__ b1, const float* __restrict__ b2,
               float alpha, int NC, int N, void* __restrict__ out_,
               const float* __restrict__ res) {
  __shared__ __align__(16) u16 Bl[2][32 * 256];
  const int tid = threadIdx.x, lane = tid & 63, wave = tid >> 6;
  const int q = lane >> 4, m = lane & 15;
  const int wm = wave >> 1, wn = wave & 1;
  const float* bias = b0;
  float al = alpha;
  size_t aoff = 0;
  const float* xsrc = X0;
  if constexpr (QKV) {
    const int y = blockIdx.y;
    aoff = (size_t)y * 12845056;  // 50176*256
    Bt += (size_t)y * 65536;
    bias = (y == 0) ? b0 : (y == 1 ? b1 : b2);
    if (y) al = 1.f;
    xsrc = (y == 0) ? X0 : (y == 1 ? X1 : X2);
  }
  const long rowBase = (long)blockIdx.x * 64;

  bf16x8 af[2][8];
  if constexpr (QKV) {
    // ---- LN1 + shift + window: 16 rows/wave -> swizzled bf16 in Bl ----
    u16* Abuf = (u16*)Bl;  // 64 x 256 (32KB)
    const float4 gv = *(const float4*)(lng + lane * 4);
    const float4 bv = *(const float4*)(lnb + lane * 4);
#pragma unroll
    for (int pp = 0; pp < 16; ++pp) {
      int lrow = wave * 16 + pp;
      size_t src = winmap((int)(rowBase + lrow));
      float4 v = *(const float4*)(xsrc + src + lane * 4);
      float sm = v.x + v.y + v.z + v.w;
      float s2 = v.x * v.x + v.y * v.y + v.z * v.z + v.w * v.w;
#pragma unroll
      for (int d = 32; d > 0; d >>= 1) {
        sm += __shfl_xor(sm, d);
        s2 += __shfl_xor(s2, d);
      }
      float mean = sm * (1.f / 256.f);
      float rstd = rsqrtf(s2 * (1.f / 256.f) - mean * mean + 1e-5f);
      ushort4 ov;
      ov.x = f2bf((v.x - mean) * rstd * gv.x + bv.x);
      ov.y = f2bf((v.y - mean) * rstd * gv.y + bv.y);
      ov.z = f2bf((v.z - mean) * rstd * gv.z + bv.z);
      ov.w = f2bf((v.w - mean) * rstd * gv.w + bv.w);
      int g = lane >> 1;
      int gs = (g & ~7) | ((g & 7) ^ (lrow & 7));
      *(ushort4*)&Abuf[lrow * 256 + gs * 8 + (lane & 1) * 4] = ov;
    }
    __syncthreads();
#pragma unroll
    for (int mt = 0; mt < 2; ++mt) {
      int row = wm * 32 + mt * 16 + m;
#pragma unroll
      for (int ks = 0; ks < 8; ++ks) {
        int g = ks * 4 + q;
        int gs = (g & ~7) | ((g & 7) ^ (row & 7));
        af[mt][ks] = *(const bf16x8*)&Abuf[row * 256 + gs * 8];
      }
    }
    __syncthreads();  // Bl free for B staging
  } else {
#pragma unroll
    for (int mt = 0; mt < 2; ++mt)
#pragma unroll
      for (int ks = 0; ks < 8; ++ks)
        af[mt][ks] = *(const bf16x8*)(Abf +
                                      (size_t)(rowBase + wm * 32 + mt * 16 + m) * 256 +
                                      ks * 32 + q * 8);
  }

  size_t obase2[2][4];
  if constexpr (EPI == 2) {
#pragma unroll
    for (int mt = 0; mt < 2; ++mt)
#pragma unroll
      for (int r = 0; r < 4; ++r)
        obase2[mt][r] = winmap((int)(rowBase + wm * 32 + mt * 16 + q * 4 + r));
  }

  auto stageB = [&](u16* dst, int c) {
#pragma unroll
    for (int it = 0; it < 4; ++it) {
      int G = it * 256 + tid;  // 1024 granules = 32 rows x 32
      int r = G >> 5, g = G & 31;
      int gs = (g & ~7) | ((g & 7) ^ (r & 7));
      gll16(Bt + (size_t)c * 8192 + r * 256 + gs * 8, dst + G * 8);
    }
  };

  stageB(Bl[0], 0);

  for (int c = 0; c < NC; ++c) {
    __syncthreads();
    if (c + 1 < NC) stageB(Bl[(c + 1) & 1], c + 1);
    const u16* Bc = Bl[c & 1];

    f32x4 acc[2] = {};
    const int rb = wn * 16 + m;
#pragma unroll
    for (int ks = 0; ks < 8; ++ks) {
      int g = ks * 4 + q;
      int gs = (g & ~7) | ((g & 7) ^ (rb & 7));
      bf16x8 bfv = *(const bf16x8*)&Bc[rb * 256 + gs * 8];
      acc[0] = __builtin_amdgcn_mfma_f32_16x16x32_bf16(af[0][ks], bfv, acc[0], 0, 0, 0);
      acc[1] = __builtin_amdgcn_mfma_f32_16x16x32_bf16(af[1][ks], bfv, acc[1], 0, 0, 0);
    }

    const int colb = c * 32 + wn * 16 + m;
    const float bvv = bias[colb];
    if constexpr (EPI == 2) {
      float* out = (float*)out_;
#pragma unroll
      for (int mt = 0; mt < 2; ++mt)
#pragma unroll
        for (int r = 0; r < 4; ++r)
          out[obase2[mt][r] + colb] = res[obase2[mt][r] + colb] + acc[mt][r] + bvv;
    } else {
      u16* out = (u16*)out_ + aoff;
#pragma unroll
      for (int mt = 0; mt < 2; ++mt) {
        size_t rw = (size_t)(rowBase + wm * 32 + mt * 16 + q * 4) * N;
#pragma unroll
        for (int r = 0; r < 4; ++r) {
          float vv = (acc[mt][r] + bvv) * al;
          out[rw + (size_t)r * N + colb] = f2bf(vv);
        }
      }
    }
  }
}

// -------------------------------- fused LN2 + FC1 + GELU + FC2 + residual ---
// 36KB LDS, 3 blocks/CU, dual-staged B1/B2. G2 REPARTITIONED BY COLUMNS:
// wave owns all 64 rows x its 64-col quarter, reading S1 from all 4 slabs
// and only its quarter of B2 -> LDS reads/hc/wave 33 -> 24 (-27%).
__global__ __launch_bounds__(256, 3)
void mlp_all(const float* __restrict__ xmid, const float* __restrict__ g2,
             const float* __restrict__ bb2, const u16* __restrict__ fw1t,
             const float* __restrict__ fb1, const u16* __restrict__ fw2t,
             const float* __restrict__ fb2, float* __restrict__ out) {
  __shared__ __align__(16) u16 bufB1[32 * 256];
  __shared__ __align__(16) u16 bufB2[256 * 32];
  __shared__ __align__(16) u16 slab[4][16 * 32];
  const int tid = threadIdx.x, lane = tid & 63, wave = tid >> 6;
  const int q = lane >> 4, m = lane & 15;
  const long rowBase = (long)blockIdx.x * 64;

  bf16x8 af[8];
  {
    const float4 gv = *(const float4*)(g2 + lane * 4);
    const float4 bv = *(const float4*)(bb2 + lane * 4);
#pragma unroll
    for (int p = 0; p < 2; ++p) {
#pragma unroll
      for (int pp = 0; pp < 8; ++pp) {
        int lrow = wave * 8 + pp;
        long grow = rowBase + p * 32 + lrow;
        float4 v = *(const float4*)(xmid + grow * 256 + lane * 4);
        float sm = v.x + v.y + v.z + v.w;
        float s2 = v.x * v.x + v.y * v.y + v.z * v.z + v.w * v.w;
#pragma unroll
        for (int d = 32; d > 0; d >>= 1) {
          sm += __shfl_xor(sm, d);
          s2 += __shfl_xor(s2, d);
        }
        float mean = sm * (1.f / 256.f);
        float rstd = rsqrtf(s2 * (1.f / 256.f) - mean * mean + 1e-5f);
        ushort4 ov;
        ov.x = f2bf((v.x - mean) * rstd * gv.x + bv.x);
        ov.y = f2bf((v.y - mean) * rstd * gv.y + bv.y);
        ov.z = f2bf((v.z - mean) * rstd * gv.z + bv.z);
        ov.w = f2bf((v.w - mean) * rstd * gv.w + bv.w);
        int g = lane >> 1;
        int gs = (g & ~7) | ((g & 7) ^ (lrow & 7));
        *(ushort4*)&bufB1[lrow * 256 + gs * 8 + (lane & 1) * 4] = ov;
      }
      __syncthreads();
      if ((wave >> 1) == p) {
        int lrow = (wave & 1) * 16 + m;
#pragma unroll
        for (int ks = 0; ks < 8; ++ks) {
          int g = ks * 4 + q;
          int gs = (g & ~7) | ((g & 7) ^ (lrow & 7));
          af[ks] = *(const bf16x8*)&bufB1[lrow * 256 + gs * 8];
        }
      }
      __syncthreads();
    }
  }

  auto stageB1 = [&](int hc) {
    const u16* src = fw1t + (size_t)hc * 8192;
#pragma unroll
    for (int it = 0; it < 4; ++it) {
      int G = it * 256 + tid;
      int r = G >> 5, g = G & 31;
      int gs = (g & ~7) | ((g & 7) ^ (r & 7));
      gll16(src + r * 256 + gs * 8, bufB1 + G * 8);
    }
  };
  auto stageB2 = [&](int hc) {
#pragma unroll
    for (int it = 0; it < 4; ++it) {
      int G = it * 256 + tid;
      int n = G >> 2, g = G & 3;
      int gs = g ^ ((n >> 1) & 3);
      gll16(fw2t + (size_t)n * 1024 + hc * 32 + gs * 8, bufB2 + G * 8);
    }
  };

  stageB1(0);

  f32x4 accO[4][4] = {};  // all 64 rows x wave's 64-col quarter
  u16* sl = slab[wave];

  for (int hc = 0; hc < 32; ++hc) {
    __syncthreads();   // B1(hc) staged+drained; bufB2 free; slab reads done
    stageB2(hc);

    // ---- G1: S1(16x32) = A @ B1^T (wave's own 16 rows) ----
    f32x4 acc1[2] = {};
#pragma unroll
    for (int ks = 0; ks < 8; ++ks) {
      int g = ks * 4 + q;
      bf16x8 bfv[2];
#pragma unroll
      for (int nt = 0; nt < 2; ++nt) {
        int r = nt * 16 + m;
        int gs = (g & ~7) | ((g & 7) ^ (r & 7));
        bfv[nt] = *(const bf16x8*)&bufB1[r * 256 + gs * 8];
      }
#pragma unroll
      for (int nt = 0; nt < 2; ++nt)
        acc1[nt] = __builtin_amdgcn_mfma_f32_16x16x32_bf16(af[ks], bfv[nt], acc1[nt], 0, 0, 0);
    }
    // bias + gelu -> per-wave slab (C-layout -> A-layout transpose)
#pragma unroll
    for (int nt = 0; nt < 2; ++nt) {
      float b1 = fb1[hc * 32 + nt * 16 + m];
      int gcol = nt * 2 + (m >> 3);
#pragma unroll
      for (int r = 0; r < 4; ++r) {
        int row = q * 4 + r;
        float h = gelu_f(acc1[nt][r] + b1);
        int gs = gcol ^ ((row >> 1) & 3);
        sl[row * 32 + gs * 8 + (m & 7)] = f2bf(h);
      }
    }
    __syncthreads();   // B2 staged+drained; all slabs visible; bufB1 free
    if (hc + 1 < 32) stageB1(hc + 1);

    // ---- G2: accO += S1(all rows) @ B2^T (wave's 64-col quarter) ----
    {
      bf16x8 pa[4], bv2[4];
#pragma unroll
      for (int mt = 0; mt < 4; ++mt) {
        int gsa = q ^ ((m >> 1) & 3);
        pa[mt] = *(const bf16x8*)&slab[mt][m * 32 + gsa * 8];
      }
#pragma unroll
      for (int nt = 0; nt < 4; ++nt) {
        int n = wave * 64 + nt * 16 + m;
        int gs2 = q ^ ((n >> 1) & 3);
        bv2[nt] = *(const bf16x8*)&bufB2[n * 32 + gs2 * 8];
      }
#pragma unroll
      for (int mt = 0; mt < 4; ++mt)
#pragma unroll
        for (int nt = 0; nt < 4; ++nt)
          accO[mt][nt] = __builtin_amdgcn_mfma_f32_16x16x32_bf16(pa[mt], bv2[nt], accO[mt][nt], 0, 0, 0);
    }
  }

  // ---- epilogue: out = xmid + accO + fb2 (block owns full rows) ----
#pragma unroll
  for (int mt = 0; mt < 4; ++mt)
#pragma unroll
    for (int nt = 0; nt < 4; ++nt) {
      int col = wave * 64 + nt * 16 + m;
      float b2 = fb2[col];
#pragma unroll
      for (int r = 0; r < 4; ++r) {
        long row = rowBase + mt * 16 + q * 4 + r;
        size_t oi = (size_t)row * 256 + col;
        out[oi] = xmid[oi] + accO[mt][nt][r] + b2;
      }
    }
}

// ------------------------------------------------------- MFMA attention -----
__global__ __launch_bounds__(64)
void attn_mfma(const u16* __restrict__ q, const u16* __restrict__ k,
               const u16* __restrict__ v, const float* __restrict__ Bp,
               u16* __restrict__ out) {
  __shared__ u16 Pl[64 * 64];
  __shared__ u16 VT[32 * 64];
  const int lane = threadIdx.x;
  const int unit = blockIdx.x;
  const int win = unit >> 3, head = unit & 7;
  const size_t base = (size_t)win * 49 * 256 + head * 32;

  {
    const int key = lane;
    const u16* vp = v + base + (size_t)key * 256;
#pragma unroll
    for (int p = 0; p < 4; ++p) {
      bf16x8 vv = {};
      if (key < 49) vv = *(const bf16x8*)(vp + p * 8);
#pragma unroll
      for (int e = 0; e < 8; ++e) {
        int dim = p * 8 + e;
        int sw = (dim ^ (dim >> 3)) & 7;
        VT[dim * 64 + ((((key >> 3) ^ sw) << 3) | (key & 7))] = (u16)vv[e];
      }
    }
  }

  const f32x4* bp = (const f32x4*)(Bp + (size_t)((win & 63) * 8 + head) * 4096);
  f32x4 acc[4][4];
#pragma unroll
  for (int mi = 0; mi < 4; ++mi)
#pragma unroll
    for (int ni = 0; ni < 4; ++ni)
      acc[mi][ni] = bp[(mi * 4 + ni) * 64 + lane];

  bf16x8 qf[4], kf[4];
#pragma unroll
  for (int mi = 0; mi < 4; ++mi)
    qf[mi] = *(const bf16x8*)(q + base + (size_t)(mi * 16 + (lane & 15)) * 256 + (lane >> 4) * 8);
#pragma unroll
  for (int ni = 0; ni < 4; ++ni)
    kf[ni] = *(const bf16x8*)(k + base + (size_t)(ni * 16 + (lane & 15)) * 256 + (lane >> 4) * 8);

#pragma unroll
  for (int mi = 0; mi < 4; ++mi)
#pragma unroll
    for (int ni = 0; ni < 4; ++ni)
      acc[mi][ni] = __builtin_amdgcn_mfma_f32_16x16x32_bf16(qf[mi], kf[ni], acc[mi][ni], 0, 0, 0);

  float rinv[4][4];
#pragma unroll
  for (int mi = 0; mi < 4; ++mi) {
#pragma unroll
    for (int r = 0; r < 4; ++r) {
      float mx = fmaxf(fmaxf(acc[mi][0][r], acc[mi][1][r]),
                       fmaxf(acc[mi][2][r], acc[mi][3][r]));
#pragma unroll
      for (int off = 1; off < 16; off <<= 1) mx = fmaxf(mx, __shfl_xor(mx, off));
      float s = 0.f;
#pragma unroll
      for (int ni = 0; ni < 4; ++ni) {
        float e = __expf(acc[mi][ni][r] - mx);
        acc[mi][ni][r] = e;
        s += e;
      }
#pragma unroll
      for (int off = 1; off < 16; off <<= 1) s += __shfl_xor(s, off);
      rinv[mi][r] = 1.f / s;
    }
  }

#pragma unroll
  for (int mi = 0; mi < 4; ++mi)
#pragma unroll
    for (int ni = 0; ni < 4; ++ni)
#pragma unroll
      for (int r = 0; r < 4; ++r) {
        int row = mi * 16 + (lane >> 4) * 4 + r;
        int col = ni * 16 + (lane & 15);
        int sw = (row ^ (row >> 3)) & 7;
        Pl[row * 64 + ((((col >> 3) ^ sw) << 3) | (col & 7))] = f2bf(acc[mi][ni][r]);
      }

  f32x4 acc2[4][2] = {};
#pragma unroll
  for (int ks = 0; ks < 2; ++ks) {
    bf16x8 pa[4], vb[2];
#pragma unroll
    for (int mi = 0; mi < 4; ++mi) {
      int row = mi * 16 + (lane & 15);
      int sw = (row ^ (row >> 3)) & 7;
      pa[mi] = *(const bf16x8*)&Pl[row * 64 + (((ks * 4 + (lane >> 4)) ^ sw) << 3)];
    }
#pragma unroll
    for (int n2 = 0; n2 < 2; ++n2) {
      int dim = n2 * 16 + (lane & 15);
      int sw = (dim ^ (dim >> 3)) & 7;
      vb[n2] = *(const bf16x8*)&VT[dim * 64 + (((ks * 4 + (lane >> 4)) ^ sw) << 3)];
    }
#pragma unroll
    for (int mi = 0; mi < 4; ++mi)
#pragma unroll
      for (int n2 = 0; n2 < 2; ++n2)
        acc2[mi][n2] = __builtin_amdgcn_mfma_f32_16x16x32_bf16(pa[mi], vb[n2], acc2[mi][n2], 0, 0, 0);
  }

#pragma unroll
  for (int mi = 0; mi < 4; ++mi)
#pragma unroll
    for (int r = 0; r < 4; ++r) {
      int row = mi * 16 + (lane >> 4) * 4 + r;
      if (row < 49) {
        float rv = rinv[mi][r];
#pragma unroll
        for (int n2 = 0; n2 < 2; ++n2) {
          int col = n2 * 16 + (lane & 15);
          out[base + (size_t)row * 256 + col] = f2bf(acc2[mi][n2][r] * rv);
        }
      }
    }
}

// ---------------------------------------------------------------- launch ----
extern "C" void kernel_launch(void* const* d_in, const int* in_sizes, int n_in,
                              void* d_out, int out_size, void* d_ws, size_t ws_size,
                              hipStream_t stream) {
  const float* x1 = (const float*)d_in[0];
  const float* x2 = (const float*)d_in[1];
  const float* x3 = (const float*)d_in[2];
  const float* amask = (const float*)d_in[3];
  const float* g1 = (const float*)d_in[4];
  const float* bb1 = (const float*)d_in[5];
  const float* wq = (const float*)d_in[6];
  const float* bq = (const float*)d_in[7];
  const float* wk = (const float*)d_in[8];
  const float* bk = (const float*)d_in[9];
  const float* wv = (const float*)d_in[10];
  const float* bvb = (const float*)d_in[11];
  const float* rel = (const float*)d_in[12];
  const float* wp = (const float*)d_in[13];
  const float* bp = (const float*)d_in[14];
  const float* g2 = (const float*)d_in[15];
  const float* bb2 = (const float*)d_in[16];
  const float* fw1 = (const float*)d_in[17];
  const float* fb1 = (const float*)d_in[18];
  const float* fw2 = (const float*)d_in[19];
  const float* fb2 = (const float*)d_in[20];

  char* wsb = (char*)d_ws;
  const size_t S = (size_t)50176 * 256 * 2;  // one bf16 token-matrix slot
  u16* attn_o = (u16*)(wsb + 0 * S);
  float* x_mid = (float*)(wsb + 1 * S);      // fp32, slots 1-2
  u16* qb = (u16*)(wsb + 3 * S);             // q,k,v contiguous (QKV y-batch)
  u16* kbuf = (u16*)(wsb + 4 * S);
  u16* vbuf = (u16*)(wsb + 5 * S);
  u16* wqt = (u16*)(wsb + 6 * S);            // wqt,wkt,wvt contiguous
  u16* wkt = wqt + 65536;
  u16* wvt = wkt + 65536;
  u16* wpt = wvt + 65536;
  u16* fw1t = wpt + 65536;
  u16* fw2t = fw1t + 262144;
  float* Bp = (float*)(fw2t + 262144);       // attn bias (8.4MB)

  prep_all<<<dim3(704), 256, 0, stream>>>(wq, wk, wv, wp, fw1, fw2, wqt, wkt,
                                          wvt, wpt, fw1t, fw2t, rel, amask, Bp);

  // QKV with fused LN1+shift+window (y selects matrix; alpha on Q only)
  gemm_k256<0, 1><<<dim3(784, 3), 256, 0, stream>>>(
      x1, x2, x3, g1, bb1, nullptr, wqt, bq, bk, bvb,
      0.17677669529663687f, 8, 256, qb, nullptr);

  attn_mfma<<<dim3(8192), 64, 0, stream>>>(qb, kbuf, vbuf, Bp, attn_o);

  // proj + win_rev + unshift + residual(x1)
  gemm_k256<2, 0><<<dim3(784), 256, 0, stream>>>(
      nullptr, nullptr, nullptr, nullptr, nullptr, attn_o, wpt, bp, bp, bp,
      1.0f, 8, 256, x_mid, x1);

  mlp_all<<<dim3(784), 256, 0, stream>>>(x_mid, g2, bb2, fw1t, fb1, fw2t, fb2,
                                         (float*)d_out);
}

// Round 17
// 304.102 us; speedup vs baseline: 1.0538x; 1.0538x over previous
//
#include <hip/hip_runtime.h>

typedef unsigned short u16;
typedef short bf16x8 __attribute__((ext_vector_type(8)));
typedef float f32x4 __attribute__((ext_vector_type(4)));

__device__ __forceinline__ u16 f2bf(float f) {
  union { float f; unsigned u; } x; x.f = f;
  unsigned r = x.u + 0x7FFFu + ((x.u >> 16) & 1u);
  return (u16)(r >> 16);
}
__device__ __forceinline__ float gelu_f(float x) {
  float t = 0.7978845608028654f * x * (1.f + 0.044715f * x * x);
  return x / (1.f + __expf(-2.f * t));
}
// async global->LDS, 16B/lane; LDS dest linear (wave-uniform base + lane*16)
__device__ __forceinline__ void gll16(const void* g, void* l) {
  __builtin_amdgcn_global_load_lds(
      (const __attribute__((address_space(1))) unsigned int*)g,
      (__attribute__((address_space(3))) unsigned int*)l, 16, 0, 0);
}
// token row -> image offset (shifted window map; same for read & reverse)
__device__ __forceinline__ size_t winmap(int t) {
  int win = t / 49, i = t - win * 49;
  int b = win >> 6, wi = win & 63;
  int ih = i / 7, iw = i - ih * 7;
  int h2 = (wi >> 3) * 7 + ih + 3; if (h2 >= 56) h2 -= 56;
  int w2 = (wi & 7) * 7 + iw + 3; if (w2 >= 56) w2 -= 56;
  return ((size_t)b * 3136 + (size_t)h2 * 56 + w2) * 256;
}

// ---------------- merged weight prep: 6 LDS-tile transposes + bias_prep -----
__global__ __launch_bounds__(256)
void prep_all(const float* __restrict__ wq, const float* __restrict__ wk,
              const float* __restrict__ wv, const float* __restrict__ wp,
              const float* __restrict__ fw1, const float* __restrict__ fw2,
              u16* __restrict__ wqt, u16* __restrict__ wkt,
              u16* __restrict__ wvt, u16* __restrict__ wpt,
              u16* __restrict__ fw1t, u16* __restrict__ fw2t,
              const float* __restrict__ rel, const float* __restrict__ mask,
              float* __restrict__ Bp) {
  const int bx = blockIdx.x;
  const int tid = threadIdx.x;
  if (bx >= 192) {  // ---- bias_prep ----
    const int blk = bx - 192;  // 0..511
    const int wi = blk >> 3, h = blk & 7;
    const float* mrow = mask + (size_t)wi * 2401;
    float* ob = Bp + (size_t)blk * 4096;
#pragma unroll
    for (int e = 0; e < 16; ++e) {
      int pos = e * 256 + tid;
      int r = pos & 3, lane = (pos >> 2) & 63, mini = pos >> 8;
      int mi = mini >> 2, ni = mini & 3;
      int row = mi * 16 + (lane >> 4) * 4 + r;
      int col = ni * 16 + (lane & 15);
      float val;
      if (col >= 49) val = -1e30f;
      else if (row >= 49) val = 0.f;
      else {
        int idx = (row / 7 - col / 7 + 6) * 13 + (row % 7 - col % 7 + 6);
        val = rel[idx * 8 + h] + mrow[row * 49 + col];
      }
      ob[pos] = val;
    }
    return;
  }
  // ---- transpose tile: out[n*K+k] = bf16(in[k*N+n]) ----
  const float* in; u16* out; int K, N, t;
  if (bx < 64) {
    int j = bx >> 4; t = bx & 15; K = 256; N = 256;
    in = j == 0 ? wq : (j == 1 ? wk : (j == 2 ? wv : wp));
    out = j == 0 ? wqt : (j == 1 ? wkt : (j == 2 ? wvt : wpt));
  } else if (bx < 128) {
    t = bx - 64; in = fw1; out = fw1t; K = 256; N = 1024;
  } else {
    t = bx - 128; in = fw2; out = fw2t; K = 1024; N = 256;
  }
  const int ntn = N >> 6;
  const int tk = t / ntn, tn = t - tk * ntn;
  __shared__ u16 tile[64][72];
#pragma unroll
  for (int it = 0; it < 4; ++it) {
    int G = it * 256 + tid;
    int kk = G >> 4, gg = G & 15;
    float4 v = *(const float4*)(in + (size_t)(tk * 64 + kk) * N + tn * 64 + gg * 4);
    tile[kk][gg * 4 + 0] = f2bf(v.x);
    tile[kk][gg * 4 + 1] = f2bf(v.y);
    tile[kk][gg * 4 + 2] = f2bf(v.z);
    tile[kk][gg * 4 + 3] = f2bf(v.w);
  }
  __syncthreads();
#pragma unroll
  for (int it = 0; it < 4; ++it) {
    int G = it * 256 + tid;
    int nn = G >> 4, gk = G & 15;
    ushort4 o;
    o.x = tile[gk * 4 + 0][nn];
    o.y = tile[gk * 4 + 1][nn];
    o.z = tile[gk * 4 + 2][nn];
    o.w = tile[gk * 4 + 3][nn];
    *(ushort4*)(out + (size_t)(tn * 64 + nn) * K + tk * 64 + gk * 4) = o;
  }
}

// ---------------------------------------------------- K=256 GEMM, A-in-regs -
// BM=64/block, 4 waves as 2M x 2N; B in 32-col LDS chunks (32KB dbuf).
// QKV=1: LN1 + cyclic-shift + window-partition fused in-LDS (A from fp32 x),
//        y batches the 3 matrices; alpha applies to Q only.
// QKV=0/EPI=2: proj; A = bf16 attn_o; fp32 scatter win_rev + residual.
template <int EPI, int QKV>
__global__ __launch_bounds__(256, 4)
void gemm_k256(const float* __restrict__ X0, const float* __restrict__ X1,
               const float* __restrict__ X2, const float* __restrict__ lng,
               const float* __restrict__ lnb, const u16* __restrict__ Abf,
               const u16* __restrict__ Bt, const float* __restrict__ b0,
               const float* __restrict__ b1, const float* __restrict__ b2,
               float alpha, int NC, int N, void* __restrict__ out_,
               const float* __restrict__ res) {
  __shared__ __align__(16) u16 Bl[2][32 * 256];
  const int tid = threadIdx.x, lane = tid & 63, wave = tid >> 6;
  const int q = lane >> 4, m = lane & 15;
  const int wm = wave >> 1, wn = wave & 1;
  const float* bias = b0;
  float al = alpha;
  size_t aoff = 0;
  const float* xsrc = X0;
  if constexpr (QKV) {
    const int y = blockIdx.y;
    aoff = (size_t)y * 12845056;  // 50176*256
    Bt += (size_t)y * 65536;
    bias = (y == 0) ? b0 : (y == 1 ? b1 : b2);
    if (y) al = 1.f;
    xsrc = (y == 0) ? X0 : (y == 1 ? X1 : X2);
  }
  const long rowBase = (long)blockIdx.x * 64;

  bf16x8 af[2][8];
  if constexpr (QKV) {
    // ---- LN1 + shift + window: 16 rows/wave -> swizzled bf16 in Bl ----
    u16* Abuf = (u16*)Bl;  // 64 x 256 (32KB)
    const float4 gv = *(const float4*)(lng + lane * 4);
    const float4 bv = *(const float4*)(lnb + lane * 4);
#pragma unroll
    for (int pp = 0; pp < 16; ++pp) {
      int lrow = wave * 16 + pp;
      size_t src = winmap((int)(rowBase + lrow));
      float4 v = *(const float4*)(xsrc + src + lane * 4);
      float sm = v.x + v.y + v.z + v.w;
      float s2 = v.x * v.x + v.y * v.y + v.z * v.z + v.w * v.w;
#pragma unroll
      for (int d = 32; d > 0; d >>= 1) {
        sm += __shfl_xor(sm, d);
        s2 += __shfl_xor(s2, d);
      }
      float mean = sm * (1.f / 256.f);
      float rstd = rsqrtf(s2 * (1.f / 256.f) - mean * mean + 1e-5f);
      ushort4 ov;
      ov.x = f2bf((v.x - mean) * rstd * gv.x + bv.x);
      ov.y = f2bf((v.y - mean) * rstd * gv.y + bv.y);
      ov.z = f2bf((v.z - mean) * rstd * gv.z + bv.z);
      ov.w = f2bf((v.w - mean) * rstd * gv.w + bv.w);
      int g = lane >> 1;
      int gs = (g & ~7) | ((g & 7) ^ (lrow & 7));
      *(ushort4*)&Abuf[lrow * 256 + gs * 8 + (lane & 1) * 4] = ov;
    }
    __syncthreads();
#pragma unroll
    for (int mt = 0; mt < 2; ++mt) {
      int row = wm * 32 + mt * 16 + m;
#pragma unroll
      for (int ks = 0; ks < 8; ++ks) {
        int g = ks * 4 + q;
        int gs = (g & ~7) | ((g & 7) ^ (row & 7));
        af[mt][ks] = *(const bf16x8*)&Abuf[row * 256 + gs * 8];
      }
    }
    __syncthreads();  // Bl free for B staging
  } else {
#pragma unroll
    for (int mt = 0; mt < 2; ++mt)
#pragma unroll
      for (int ks = 0; ks < 8; ++ks)
        af[mt][ks] = *(const bf16x8*)(Abf +
                                      (size_t)(rowBase + wm * 32 + mt * 16 + m) * 256 +
                                      ks * 32 + q * 8);
  }

  size_t obase2[2][4];
  if constexpr (EPI == 2) {
#pragma unroll
    for (int mt = 0; mt < 2; ++mt)
#pragma unroll
      for (int r = 0; r < 4; ++r)
        obase2[mt][r] = winmap((int)(rowBase + wm * 32 + mt * 16 + q * 4 + r));
  }

  auto stageB = [&](u16* dst, int c) {
#pragma unroll
    for (int it = 0; it < 4; ++it) {
      int G = it * 256 + tid;  // 1024 granules = 32 rows x 32
      int r = G >> 5, g = G & 31;
      int gs = (g & ~7) | ((g & 7) ^ (r & 7));
      gll16(Bt + (size_t)c * 8192 + r * 256 + gs * 8, dst + G * 8);
    }
  };

  stageB(Bl[0], 0);

  for (int c = 0; c < NC; ++c) {
    __syncthreads();
    if (c + 1 < NC) stageB(Bl[(c + 1) & 1], c + 1);
    const u16* Bc = Bl[c & 1];

    f32x4 acc[2] = {};
    const int rb = wn * 16 + m;
#pragma unroll
    for (int ks = 0; ks < 8; ++ks) {
      int g = ks * 4 + q;
      int gs = (g & ~7) | ((g & 7) ^ (rb & 7));
      bf16x8 bfv = *(const bf16x8*)&Bc[rb * 256 + gs * 8];
      acc[0] = __builtin_amdgcn_mfma_f32_16x16x32_bf16(af[0][ks], bfv, acc[0], 0, 0, 0);
      acc[1] = __builtin_amdgcn_mfma_f32_16x16x32_bf16(af[1][ks], bfv, acc[1], 0, 0, 0);
    }

    const int colb = c * 32 + wn * 16 + m;
    const float bvv = bias[colb];
    if constexpr (EPI == 2) {
      float* out = (float*)out_;
#pragma unroll
      for (int mt = 0; mt < 2; ++mt)
#pragma unroll
        for (int r = 0; r < 4; ++r)
          out[obase2[mt][r] + colb] = res[obase2[mt][r] + colb] + acc[mt][r] + bvv;
    } else {
      u16* out = (u16*)out_ + aoff;
#pragma unroll
      for (int mt = 0; mt < 2; ++mt) {
        size_t rw = (size_t)(rowBase + wm * 32 + mt * 16 + q * 4) * N;
#pragma unroll
        for (int r = 0; r < 4; ++r) {
          float vv = (acc[mt][r] + bvv) * al;
          out[rw + (size_t)r * N + colb] = f2bf(vv);
        }
      }
    }
  }
}

// -------------------------------- fused LN2 + FC1 + GELU + FC2 + residual ---
// Single-barrier double-buffered schedule: prefetch B1/B2(hc+1) into alt
// buffers at loop top, compute G1->gelu->G2 (own slab, no barrier needed)
// from current buffers, ONE trailing barrier per hc (drain + swap protect).
// LDS 68KB -> 2 blocks/CU. Epilogue: wave owns full rows (write clustering).
__global__ __launch_bounds__(256, 2)
void mlp_all(const float* __restrict__ xmid, const float* __restrict__ g2,
             const float* __restrict__ bb2, const u16* __restrict__ fw1t,
             const float* __restrict__ fb1, const u16* __restrict__ fw2t,
             const float* __restrict__ fb2, float* __restrict__ out) {
  __shared__ __align__(16) u16 bufB1[2][32 * 256];   // 32KB
  __shared__ __align__(16) u16 bufB2[2][256 * 32];   // 32KB
  __shared__ __align__(16) u16 slab[4][16 * 32];     // 4KB
  const int tid = threadIdx.x, lane = tid & 63, wave = tid >> 6;
  const int q = lane >> 4, m = lane & 15;
  const long rowBase = (long)blockIdx.x * 64;

  // ---- LN2 -> full 64x256 across both bufB1 halves; A frags -> registers ---
  bf16x8 af[8];
  {
    u16* Afull = (u16*)bufB1;  // 64 x 256 (32KB)
    const float4 gv = *(const float4*)(g2 + lane * 4);
    const float4 bv = *(const float4*)(bb2 + lane * 4);
#pragma unroll
    for (int pp = 0; pp < 16; ++pp) {
      int lrow = wave * 16 + pp;
      float4 v = *(const float4*)(xmid + (rowBase + lrow) * 256 + lane * 4);
      float sm = v.x + v.y + v.z + v.w;
      float s2 = v.x * v.x + v.y * v.y + v.z * v.z + v.w * v.w;
#pragma unroll
      for (int d = 32; d > 0; d >>= 1) {
        sm += __shfl_xor(sm, d);
        s2 += __shfl_xor(s2, d);
      }
      float mean = sm * (1.f / 256.f);
      float rstd = rsqrtf(s2 * (1.f / 256.f) - mean * mean + 1e-5f);
      ushort4 ov;
      ov.x = f2bf((v.x - mean) * rstd * gv.x + bv.x);
      ov.y = f2bf((v.y - mean) * rstd * gv.y + bv.y);
      ov.z = f2bf((v.z - mean) * rstd * gv.z + bv.z);
      ov.w = f2bf((v.w - mean) * rstd * gv.w + bv.w);
      int g = lane >> 1;
      int gs = (g & ~7) | ((g & 7) ^ (lrow & 7));
      *(ushort4*)&Afull[lrow * 256 + gs * 8 + (lane & 1) * 4] = ov;
    }
    __syncthreads();
    int row = wave * 16 + m;
#pragma unroll
    for (int ks = 0; ks < 8; ++ks) {
      int g = ks * 4 + q;
      int gs = (g & ~7) | ((g & 7) ^ (row & 7));
      af[ks] = *(const bf16x8*)&Afull[row * 256 + gs * 8];
    }
    __syncthreads();  // bufB1 free for staging
  }

  auto stageB1 = [&](int hc, u16* dst) {  // fw1t rows [hc*32,+32) x 256
    const u16* src = fw1t + (size_t)hc * 8192;
#pragma unroll
    for (int it = 0; it < 4; ++it) {
      int G = it * 256 + tid;
      int r = G >> 5, g = G & 31;
      int gs = (g & ~7) | ((g & 7) ^ (r & 7));
      gll16(src + r * 256 + gs * 8, dst + G * 8);
    }
  };
  auto stageB2 = [&](int hc, u16* dst) {  // fw2t 256 rows, k-cols [hc*32,+32)
#pragma unroll
    for (int it = 0; it < 4; ++it) {
      int G = it * 256 + tid;
      int n = G >> 2, g = G & 3;
      int gs = g ^ ((n >> 1) & 3);
      gll16(fw2t + (size_t)n * 1024 + hc * 32 + gs * 8, dst + G * 8);
    }
  };

  stageB1(0, bufB1[0]);
  stageB2(0, bufB2[0]);
  __syncthreads();  // buffers 0 ready

  f32x4 accO[16] = {};  // wave's 16 rows x 256 out cols
  u16* sl = slab[wave];

  for (int hc = 0; hc < 32; ++hc) {
    const int cur = hc & 1;
    if (hc + 1 < 32) {
      stageB1(hc + 1, bufB1[cur ^ 1]);
      stageB2(hc + 1, bufB2[cur ^ 1]);
    }

    // ---- G1: S1(16x32) = A @ B1^T (wave's own 16 rows) ----
    f32x4 acc1[2] = {};
#pragma unroll
    for (int ks = 0; ks < 8; ++ks) {
      int g = ks * 4 + q;
      bf16x8 bfv[2];
#pragma unroll
      for (int nt = 0; nt < 2; ++nt) {
        int r = nt * 16 + m;
        int gs = (g & ~7) | ((g & 7) ^ (r & 7));
        bfv[nt] = *(const bf16x8*)&bufB1[cur][r * 256 + gs * 8];
      }
#pragma unroll
      for (int nt = 0; nt < 2; ++nt)
        acc1[nt] = __builtin_amdgcn_mfma_f32_16x16x32_bf16(af[ks], bfv[nt], acc1[nt], 0, 0, 0);
    }
    // bias + gelu -> own slab (wave-private; lgkm ordering handled by compiler)
#pragma unroll
    for (int nt = 0; nt < 2; ++nt) {
      float b1 = fb1[hc * 32 + nt * 16 + m];
      int gcol = nt * 2 + (m >> 3);
#pragma unroll
      for (int r = 0; r < 4; ++r) {
        int row = q * 4 + r;
        float h = gelu_f(acc1[nt][r] + b1);
        int gs = gcol ^ ((row >> 1) & 3);
        sl[row * 32 + gs * 8 + (m & 7)] = f2bf(h);
      }
    }

    // ---- G2: accO += S1 @ B2^T (own slab + current B2) ----
    {
      int gsa = q ^ ((m >> 1) & 3);
      bf16x8 pa = *(const bf16x8*)&sl[m * 32 + gsa * 8];
#pragma unroll
      for (int nt = 0; nt < 16; ++nt) {
        int n = nt * 16 + m;
        int gs2 = q ^ ((n >> 1) & 3);
        bf16x8 bv2 = *(const bf16x8*)&bufB2[cur][n * 32 + gs2 * 8];
        accO[nt] = __builtin_amdgcn_mfma_f32_16x16x32_bf16(pa, bv2, accO[nt], 0, 0, 0);
      }
    }
    __syncthreads();  // ONE barrier/hc: drains prefetch, protects buffer swap
  }

  // ---- epilogue: out = xmid + accO + fb2 (wave owns full rows) ----
#pragma unroll
  for (int nt = 0; nt < 16; ++nt) {
    int col = nt * 16 + m;
    float b2 = fb2[col];
#pragma unroll
    for (int r = 0; r < 4; ++r) {
      long row = rowBase + wave * 16 + q * 4 + r;
      size_t oi = (size_t)row * 256 + col;
      out[oi] = xmid[oi] + accO[nt][r] + b2;
    }
  }
}

// ------------------------------------------------------- MFMA attention -----
__global__ __launch_bounds__(64)
void attn_mfma(const u16* __restrict__ q, const u16* __restrict__ k,
               const u16* __restrict__ v, const float* __restrict__ Bp,
               u16* __restrict__ out) {
  __shared__ u16 Pl[64 * 64];
  __shared__ u16 VT[32 * 64];
  const int lane = threadIdx.x;
  const int unit = blockIdx.x;
  const int win = unit >> 3, head = unit & 7;
  const size_t base = (size_t)win * 49 * 256 + head * 32;

  {
    const int key = lane;
    const u16* vp = v + base + (size_t)key * 256;
#pragma unroll
    for (int p = 0; p < 4; ++p) {
      bf16x8 vv = {};
      if (key < 49) vv = *(const bf16x8*)(vp + p * 8);
#pragma unroll
      for (int e = 0; e < 8; ++e) {
        int dim = p * 8 + e;
        int sw = (dim ^ (dim >> 3)) & 7;
        VT[dim * 64 + ((((key >> 3) ^ sw) << 3) | (key & 7))] = (u16)vv[e];
      }
    }
  }

  const f32x4* bp = (const f32x4*)(Bp + (size_t)((win & 63) * 8 + head) * 4096);
  f32x4 acc[4][4];
#pragma unroll
  for (int mi = 0; mi < 4; ++mi)
#pragma unroll
    for (int ni = 0; ni < 4; ++ni)
      acc[mi][ni] = bp[(mi * 4 + ni) * 64 + lane];

  bf16x8 qf[4], kf[4];
#pragma unroll
  for (int mi = 0; mi < 4; ++mi)
    qf[mi] = *(const bf16x8*)(q + base + (size_t)(mi * 16 + (lane & 15)) * 256 + (lane >> 4) * 8);
#pragma unroll
  for (int ni = 0; ni < 4; ++ni)
    kf[ni] = *(const bf16x8*)(k + base + (size_t)(ni * 16 + (lane & 15)) * 256 + (lane >> 4) * 8);

#pragma unroll
  for (int mi = 0; mi < 4; ++mi)
#pragma unroll
    for (int ni = 0; ni < 4; ++ni)
      acc[mi][ni] = __builtin_amdgcn_mfma_f32_16x16x32_bf16(qf[mi], kf[ni], acc[mi][ni], 0, 0, 0);

  float rinv[4][4];
#pragma unroll
  for (int mi = 0; mi < 4; ++mi) {
#pragma unroll
    for (int r = 0; r < 4; ++r) {
      float mx = fmaxf(fmaxf(acc[mi][0][r], acc[mi][1][r]),
                       fmaxf(acc[mi][2][r], acc[mi][3][r]));
#pragma unroll
      for (int off = 1; off < 16; off <<= 1) mx = fmaxf(mx, __shfl_xor(mx, off));
      float s = 0.f;
#pragma unroll
      for (int ni = 0; ni < 4; ++ni) {
        float e = __expf(acc[mi][ni][r] - mx);
        acc[mi][ni][r] = e;
        s += e;
      }
#pragma unroll
      for (int off = 1; off < 16; off <<= 1) s += __shfl_xor(s, off);
      rinv[mi][r] = 1.f / s;
    }
  }

#pragma unroll
  for (int mi = 0; mi < 4; ++mi)
#pragma unroll
    for (int ni = 0; ni < 4; ++ni)
#pragma unroll
      for (int r = 0; r < 4; ++r) {
        int row = mi * 16 + (lane >> 4) * 4 + r;
        int col = ni * 16 + (lane & 15);
        int sw = (row ^ (row >> 3)) & 7;
        Pl[row * 64 + ((((col >> 3) ^ sw) << 3) | (col & 7))] = f2bf(acc[mi][ni][r]);
      }

  f32x4 acc2[4][2] = {};
#pragma unroll
  for (int ks = 0; ks < 2; ++ks) {
    bf16x8 pa[4], vb[2];
#pragma unroll
    for (int mi = 0; mi < 4; ++mi) {
      int row = mi * 16 + (lane & 15);
      int sw = (row ^ (row >> 3)) & 7;
      pa[mi] = *(const bf16x8*)&Pl[row * 64 + (((ks * 4 + (lane >> 4)) ^ sw) << 3)];
    }
#pragma unroll
    for (int n2 = 0; n2 < 2; ++n2) {
      int dim = n2 * 16 + (lane & 15);
      int sw = (dim ^ (dim >> 3)) & 7;
      vb[n2] = *(const bf16x8*)&VT[dim * 64 + (((ks * 4 + (lane >> 4)) ^ sw) << 3)];
    }
#pragma unroll
    for (int mi = 0; mi < 4; ++mi)
#pragma unroll
      for (int n2 = 0; n2 < 2; ++n2)
        acc2[mi][n2] = __builtin_amdgcn_mfma_f32_16x16x32_bf16(pa[mi], vb[n2], acc2[mi][n2], 0, 0, 0);
  }

#pragma unroll
  for (int mi = 0; mi < 4; ++mi)
#pragma unroll
    for (int r = 0; r < 4; ++r) {
      int row = mi * 16 + (lane >> 4) * 4 + r;
      if (row < 49) {
        float rv = rinv[mi][r];
#pragma unroll
        for (int n2 = 0; n2 < 2; ++n2) {
          int col = n2 * 16 + (lane & 15);
          out[base + (size_t)row * 256 + col] = f2bf(acc2[mi][n2][r] * rv);
        }
      }
    }
}

// ---------------------------------------------------------------- launch ----
extern "C" void kernel_launch(void* const* d_in, const int* in_sizes, int n_in,
                              void* d_out, int out_size, void* d_ws, size_t ws_size,
                              hipStream_t stream) {
  const float* x1 = (const float*)d_in[0];
  const float* x2 = (const float*)d_in[1];
  const float* x3 = (const float*)d_in[2];
  const float* amask = (const float*)d_in[3];
  const float* g1 = (const float*)d_in[4];
  const float* bb1 = (const float*)d_in[5];
  const float* wq = (const float*)d_in[6];
  const float* bq = (const float*)d_in[7];
  const float* wk = (const float*)d_in[8];
  const float* bk = (const float*)d_in[9];
  const float* wv = (const float*)d_in[10];
  const float* bvb = (const float*)d_in[11];
  const float* rel = (const float*)d_in[12];
  const float* wp = (const float*)d_in[13];
  const float* bp = (const float*)d_in[14];
  const float* g2 = (const float*)d_in[15];
  const float* bb2 = (const float*)d_in[16];
  const float* fw1 = (const float*)d_in[17];
  const float* fb1 = (const float*)d_in[18];
  const float* fw2 = (const float*)d_in[19];
  const float* fb2 = (const float*)d_in[20];

  char* wsb = (char*)d_ws;
  const size_t S = (size_t)50176 * 256 * 2;  // one bf16 token-matrix slot
  u16* attn_o = (u16*)(wsb + 0 * S);
  float* x_mid = (float*)(wsb + 1 * S);      // fp32, slots 1-2
  u16* qb = (u16*)(wsb + 3 * S);             // q,k,v contiguous (QKV y-batch)
  u16* kbuf = (u16*)(wsb + 4 * S);
  u16* vbuf = (u16*)(wsb + 5 * S);
  u16* wqt = (u16*)(wsb + 6 * S);            // wqt,wkt,wvt contiguous
  u16* wkt = wqt + 65536;
  u16* wvt = wkt + 65536;
  u16* wpt = wvt + 65536;
  u16* fw1t = wpt + 65536;
  u16* fw2t = fw1t + 262144;
  float* Bp = (float*)(fw2t + 262144);       // attn bias (8.4MB)

  prep_all<<<dim3(704), 256, 0, stream>>>(wq, wk, wv, wp, fw1, fw2, wqt, wkt,
                                          wvt, wpt, fw1t, fw2t, rel, amask, Bp);

  // QKV with fused LN1+shift+window (y selects matrix; alpha on Q only)
  gemm_k256<0, 1><<<dim3(784, 3), 256, 0, stream>>>(
      x1, x2, x3, g1, bb1, nullptr, wqt, bq, bk, bvb,
      0.17677669529663687f, 8, 256, qb, nullptr);

  attn_mfma<<<dim3(8192), 64, 0, stream>>>(qb, kbuf, vbuf, Bp, attn_o);

  // proj + win_rev + unshift + residual(x1)
  gemm_k256<2, 0><<<dim3(784), 256, 0, stream>>>(
      nullptr, nullptr, nullptr, nullptr, nullptr, attn_o, wpt, bp, bp, bp,
      1.0f, 8, 256, x_mid, x1);

  mlp_all<<<dim3(784), 256, 0, stream>>>(x_mid, g2, bb2, fw1t, fb1, fw2t, fb2,
                                         (float*)d_out);
}

// Round 18
// 257.011 us; speedup vs baseline: 1.2468x; 1.1832x over previous
//
#include <hip/hip_runtime.h>

typedef unsigned short u16;
typedef short bf16x8 __attribute__((ext_vector_type(8)));
typedef float f32x4 __attribute__((ext_vector_type(4)));

__device__ __forceinline__ u16 f2bf(float f) {
  union { float f; unsigned u; } x; x.f = f;
  unsigned r = x.u + 0x7FFFu + ((x.u >> 16) & 1u);
  return (u16)(r >> 16);
}
__device__ __forceinline__ float bf2f(u16 u) {
  union { unsigned u; float f; } x; x.u = (unsigned)u << 16; return x.f;
}
__device__ __forceinline__ float gelu_f(float x) {
  float t = 0.7978845608028654f * x * (1.f + 0.044715f * x * x);
  return x / (1.f + __expf(-2.f * t));
}
// async global->LDS, 16B/lane; LDS dest linear (wave-uniform base + lane*16)
__device__ __forceinline__ void gll16(const void* g, void* l) {
  __builtin_amdgcn_global_load_lds(
      (const __attribute__((address_space(1))) unsigned int*)g,
      (__attribute__((address_space(3))) unsigned int*)l, 16, 0, 0);
}
// token row -> image offset (shifted window map; same for read & reverse)
__device__ __forceinline__ size_t winmap(int t) {
  int win = t / 49, i = t - win * 49;
  int b = win >> 6, wi = win & 63;
  int ih = i / 7, iw = i - ih * 7;
  int h2 = (wi >> 3) * 7 + ih + 3; if (h2 >= 56) h2 -= 56;
  int w2 = (wi & 7) * 7 + iw + 3; if (w2 >= 56) w2 -= 56;
  return ((size_t)b * 3136 + (size_t)h2 * 56 + w2) * 256;
}

// ---------------- merged weight prep: 6 LDS-tile transposes + bias_prep -----
__global__ __launch_bounds__(256)
void prep_all(const float* __restrict__ wq, const float* __restrict__ wk,
              const float* __restrict__ wv, const float* __restrict__ wp,
              const float* __restrict__ fw1, const float* __restrict__ fw2,
              u16* __restrict__ wqt, u16* __restrict__ wkt,
              u16* __restrict__ wvt, u16* __restrict__ wpt,
              u16* __restrict__ fw1t, u16* __restrict__ fw2t,
              const float* __restrict__ rel, const float* __restrict__ mask,
              float* __restrict__ Bp) {
  const int bx = blockIdx.x;
  const int tid = threadIdx.x;
  if (bx >= 192) {  // ---- bias_prep ----
    const int blk = bx - 192;  // 0..511
    const int wi = blk >> 3, h = blk & 7;
    const float* mrow = mask + (size_t)wi * 2401;
    float* ob = Bp + (size_t)blk * 4096;
#pragma unroll
    for (int e = 0; e < 16; ++e) {
      int pos = e * 256 + tid;
      int r = pos & 3, lane = (pos >> 2) & 63, mini = pos >> 8;
      int mi = mini >> 2, ni = mini & 3;
      int row = mi * 16 + (lane >> 4) * 4 + r;
      int col = ni * 16 + (lane & 15);
      float val;
      if (col >= 49) val = -1e30f;
      else if (row >= 49) val = 0.f;
      else {
        int idx = (row / 7 - col / 7 + 6) * 13 + (row % 7 - col % 7 + 6);
        val = rel[idx * 8 + h] + mrow[row * 49 + col];
      }
      ob[pos] = val;
    }
    return;
  }
  // ---- transpose tile: out[n*K+k] = bf16(in[k*N+n]) ----
  const float* in; u16* out; int K, N, t;
  if (bx < 64) {
    int j = bx >> 4; t = bx & 15; K = 256; N = 256;
    in = j == 0 ? wq : (j == 1 ? wk : (j == 2 ? wv : wp));
    out = j == 0 ? wqt : (j == 1 ? wkt : (j == 2 ? wvt : wpt));
  } else if (bx < 128) {
    t = bx - 64; in = fw1; out = fw1t; K = 256; N = 1024;
  } else {
    t = bx - 128; in = fw2; out = fw2t; K = 1024; N = 256;
  }
  const int ntn = N >> 6;
  const int tk = t / ntn, tn = t - tk * ntn;
  __shared__ u16 tile[64][72];
#pragma unroll
  for (int it = 0; it < 4; ++it) {
    int G = it * 256 + tid;
    int kk = G >> 4, gg = G & 15;
    float4 v = *(const float4*)(in + (size_t)(tk * 64 + kk) * N + tn * 64 + gg * 4);
    tile[kk][gg * 4 + 0] = f2bf(v.x);
    tile[kk][gg * 4 + 1] = f2bf(v.y);
    tile[kk][gg * 4 + 2] = f2bf(v.z);
    tile[kk][gg * 4 + 3] = f2bf(v.w);
  }
  __syncthreads();
#pragma unroll
  for (int it = 0; it < 4; ++it) {
    int G = it * 256 + tid;
    int nn = G >> 4, gk = G & 15;
    ushort4 o;
    o.x = tile[gk * 4 + 0][nn];
    o.y = tile[gk * 4 + 1][nn];
    o.z = tile[gk * 4 + 2][nn];
    o.w = tile[gk * 4 + 3][nn];
    *(ushort4*)(out + (size_t)(tn * 64 + nn) * K + tk * 64 + gk * 4) = o;
  }
}

// ---------------------------------------------------- QKV GEMM, A-in-regs ---
// BM=64/block, 4 waves as 2M x 2N; B in 32-col LDS chunks (32KB dbuf).
// LN1 + cyclic-shift + window-partition fused in-LDS; y batches the 3
// matrices; alpha applies to Q only.
__global__ __launch_bounds__(256, 4)
void gemm_qkv(const float* __restrict__ X0, const float* __restrict__ X1,
              const float* __restrict__ X2, const float* __restrict__ lng,
              const float* __restrict__ lnb, const u16* __restrict__ Bt,
              const float* __restrict__ b0, const float* __restrict__ b1,
              const float* __restrict__ b2, float alpha,
              u16* __restrict__ out_) {
  __shared__ __align__(16) u16 Bl[2][32 * 256];
  const int tid = threadIdx.x, lane = tid & 63, wave = tid >> 6;
  const int q = lane >> 4, m = lane & 15;
  const int wm = wave >> 1, wn = wave & 1;
  const int y = blockIdx.y;
  const size_t aoff = (size_t)y * 12845056;  // 50176*256
  Bt += (size_t)y * 65536;
  const float* bias = (y == 0) ? b0 : (y == 1 ? b1 : b2);
  const float al = (y == 0) ? alpha : 1.f;
  const float* xsrc = (y == 0) ? X0 : (y == 1 ? X1 : X2);
  const long rowBase = (long)blockIdx.x * 64;

  bf16x8 af[2][8];
  {
    // ---- LN1 + shift + window: 16 rows/wave -> swizzled bf16 in Bl ----
    u16* Abuf = (u16*)Bl;  // 64 x 256 (32KB)
    const float4 gv = *(const float4*)(lng + lane * 4);
    const float4 bv = *(const float4*)(lnb + lane * 4);
#pragma unroll
    for (int pp = 0; pp < 16; ++pp) {
      int lrow = wave * 16 + pp;
      size_t src = winmap((int)(rowBase + lrow));
      float4 v = *(const float4*)(xsrc + src + lane * 4);
      float sm = v.x + v.y + v.z + v.w;
      float s2 = v.x * v.x + v.y * v.y + v.z * v.z + v.w * v.w;
#pragma unroll
      for (int d = 32; d > 0; d >>= 1) {
        sm += __shfl_xor(sm, d);
        s2 += __shfl_xor(s2, d);
      }
      float mean = sm * (1.f / 256.f);
      float rstd = rsqrtf(s2 * (1.f / 256.f) - mean * mean + 1e-5f);
      ushort4 ov;
      ov.x = f2bf((v.x - mean) * rstd * gv.x + bv.x);
      ov.y = f2bf((v.y - mean) * rstd * gv.y + bv.y);
      ov.z = f2bf((v.z - mean) * rstd * gv.z + bv.z);
      ov.w = f2bf((v.w - mean) * rstd * gv.w + bv.w);
      int g = lane >> 1;
      int gs = (g & ~7) | ((g & 7) ^ (lrow & 7));
      *(ushort4*)&Abuf[lrow * 256 + gs * 8 + (lane & 1) * 4] = ov;
    }
    __syncthreads();
#pragma unroll
    for (int mt = 0; mt < 2; ++mt) {
      int row = wm * 32 + mt * 16 + m;
#pragma unroll
      for (int ks = 0; ks < 8; ++ks) {
        int g = ks * 4 + q;
        int gs = (g & ~7) | ((g & 7) ^ (row & 7));
        af[mt][ks] = *(const bf16x8*)&Abuf[row * 256 + gs * 8];
      }
    }
    __syncthreads();  // Bl free for B staging
  }

  auto stageB = [&](u16* dst, int c) {
#pragma unroll
    for (int it = 0; it < 4; ++it) {
      int G = it * 256 + tid;  // 1024 granules = 32 rows x 32
      int r = G >> 5, g = G & 31;
      int gs = (g & ~7) | ((g & 7) ^ (r & 7));
      gll16(Bt + (size_t)c * 8192 + r * 256 + gs * 8, dst + G * 8);
    }
  };

  stageB(Bl[0], 0);

  for (int c = 0; c < 8; ++c) {
    __syncthreads();
    if (c + 1 < 8) stageB(Bl[(c + 1) & 1], c + 1);
    const u16* Bc = Bl[c & 1];

    f32x4 acc[2] = {};
    const int rb = wn * 16 + m;
#pragma unroll
    for (int ks = 0; ks < 8; ++ks) {
      int g = ks * 4 + q;
      int gs = (g & ~7) | ((g & 7) ^ (rb & 7));
      bf16x8 bfv = *(const bf16x8*)&Bc[rb * 256 + gs * 8];
      acc[0] = __builtin_amdgcn_mfma_f32_16x16x32_bf16(af[0][ks], bfv, acc[0], 0, 0, 0);
      acc[1] = __builtin_amdgcn_mfma_f32_16x16x32_bf16(af[1][ks], bfv, acc[1], 0, 0, 0);
    }

    const int colb = c * 32 + wn * 16 + m;
    const float bvv = bias[colb];
    u16* out = out_ + aoff;
#pragma unroll
    for (int mt = 0; mt < 2; ++mt) {
      size_t rw = (size_t)(rowBase + wm * 32 + mt * 16 + q * 4) * 256;
#pragma unroll
      for (int r = 0; r < 4; ++r) {
        float vv = (acc[mt][r] + bvv) * al;
        out[rw + (size_t)r * 256 + colb] = f2bf(vv);
      }
    }
  }
}

// ------------- fused proj + win_rev + residual + LN2 + FC1+GELU+FC2 ---------
// Grid 784 x 64 token-rows, 4 waves (each owns 16 rows for ALL phases).
// xbuf (32KB bf16) holds x = proj+bias+x1 block-locally (never hits HBM).
// LDS 68KB -> 2 blocks/CU. MLP loop = R15-proven 2-barrier schedule.
__global__ __launch_bounds__(256, 2)
void proj_mlp(const u16* __restrict__ attn_o, const u16* __restrict__ wpt,
              const float* __restrict__ bpj, const float* __restrict__ x1,
              const float* __restrict__ g2, const float* __restrict__ bb2,
              const u16* __restrict__ fw1t, const float* __restrict__ fb1,
              const u16* __restrict__ fw2t, const float* __restrict__ fb2,
              float* __restrict__ out) {
  __shared__ __align__(16) u16 xbuf[64 * 256];    // 32KB: x rows (bf16, swz)
  __shared__ __align__(16) u16 Bd0[32 * 256];     // 16KB: wpt / fw1t chunks
  __shared__ __align__(16) u16 Bd1[256 * 32];     // 16KB: wpt / fw2t chunks
  __shared__ __align__(16) u16 slab[4][16 * 32];  // 4KB: per-wave S1
  const int tid = threadIdx.x, lane = tid & 63, wave = tid >> 6;
  const int q = lane >> 4, m = lane & 15;
  const long rowBase = (long)blockIdx.x * 64;

  // thread's 4 image-row offsets (rows wave*16 + q*4 + r) — proj res + final out
  size_t obaseP[4];
#pragma unroll
  for (int r = 0; r < 4; ++r)
    obaseP[r] = winmap((int)(rowBase + wave * 16 + q * 4 + r));

  // ---- proj A fragments: wave's 16 rows of attn_o (read once) ----
  bf16x8 afP[8];
  {
    const u16* ap = attn_o + (size_t)(rowBase + wave * 16 + m) * 256 + q * 8;
#pragma unroll
    for (int ks = 0; ks < 8; ++ks) afP[ks] = *(const bf16x8*)(ap + ks * 32);
  }

  auto stageW = [&](int c, u16* dst) {  // wpt rows [c*32,+32) x 256
    const u16* src = wpt + (size_t)c * 8192;
#pragma unroll
    for (int it = 0; it < 4; ++it) {
      int G = it * 256 + tid;
      int r = G >> 5, g = G & 31;
      int gs = (g & ~7) | ((g & 7) ^ (r & 7));
      gll16(src + r * 256 + gs * 8, dst + G * 8);
    }
  };
  auto stageB1 = [&](int hc) {  // fw1t rows [hc*32,+32) x 256 -> Bd0
    const u16* src = fw1t + (size_t)hc * 8192;
#pragma unroll
    for (int it = 0; it < 4; ++it) {
      int G = it * 256 + tid;
      int r = G >> 5, g = G & 31;
      int gs = (g & ~7) | ((g & 7) ^ (r & 7));
      gll16(src + r * 256 + gs * 8, Bd0 + G * 8);
    }
  };
  auto stageB2 = [&](int hc) {  // fw2t 256 rows, k-cols [hc*32,+32) -> Bd1
#pragma unroll
    for (int it = 0; it < 4; ++it) {
      int G = it * 256 + tid;
      int n = G >> 2, g = G & 3;
      int gs = g ^ ((n >> 1) & 3);
      gll16(fw2t + (size_t)n * 1024 + hc * 32 + gs * 8, Bd1 + G * 8);
    }
  };

  // ======================= Phase A: proj -> xbuf ===========================
  stageW(0, Bd0);
  for (int c = 0; c < 8; ++c) {
    __syncthreads();  // drains stage for chunk c; protects buffer reuse
    if (c + 1 < 8) stageW(c + 1, (c & 1) ? Bd0 : Bd1);
    const u16* Bc = (c & 1) ? Bd1 : Bd0;

    f32x4 acc1[2] = {};
#pragma unroll
    for (int ks = 0; ks < 8; ++ks) {
      int g = ks * 4 + q;
      bf16x8 bfv[2];
#pragma unroll
      for (int nt = 0; nt < 2; ++nt) {
        int rb = nt * 16 + m;
        int gs = (g & ~7) | ((g & 7) ^ (rb & 7));
        bfv[nt] = *(const bf16x8*)&Bc[rb * 256 + gs * 8];
      }
#pragma unroll
      for (int nt = 0; nt < 2; ++nt)
        acc1[nt] = __builtin_amdgcn_mfma_f32_16x16x32_bf16(afP[ks], bfv[nt], acc1[nt], 0, 0, 0);
    }
    // x = proj + bias + x1  -> xbuf (bf16, swizzled; wave-private rows)
#pragma unroll
    for (int nt = 0; nt < 2; ++nt) {
      int col = c * 32 + nt * 16 + m;
      float bvv = bpj[col];
      int g = col >> 3;
#pragma unroll
      for (int r = 0; r < 4; ++r) {
        int row = wave * 16 + q * 4 + r;
        float v = acc1[nt][r] + bvv + x1[obaseP[r] + col];
        int gs = (g & ~7) | ((g & 7) ^ (row & 7));
        xbuf[row * 256 + gs * 8 + (col & 7)] = f2bf(v);
      }
    }
  }
  // all waves past chunk 6; Bd0's last read was chunk 6 -> safe to restage
  stageB1(0);

  // =============== Phase B: LN2 from xbuf (own rows, no barrier) ===========
  float meanK = 0.f, rstdK = 0.f;
#pragma unroll
  for (int rr = 0; rr < 16; ++rr) {
    int row = wave * 16 + rr;
    ushort4 xv = *(const ushort4*)&xbuf[row * 256 + lane * 4];
    float a0 = bf2f(xv.x), a1 = bf2f(xv.y), a2 = bf2f(xv.z), a3 = bf2f(xv.w);
    float s = a0 + a1 + a2 + a3;
    float s2 = a0 * a0 + a1 * a1 + a2 * a2 + a3 * a3;
#pragma unroll
    for (int d = 32; d > 0; d >>= 1) {
      s += __shfl_xor(s, d);
      s2 += __shfl_xor(s2, d);
    }
    float mean = s * (1.f / 256.f);
    float rstd = rsqrtf(s2 * (1.f / 256.f) - mean * mean + 1e-5f);
    if ((lane & 15) == rr) { meanK = mean; rstdK = rstd; }
  }
  bf16x8 af[8];
  {
    int row = wave * 16 + m;
#pragma unroll
    for (int ks = 0; ks < 8; ++ks) {
      int g = ks * 4 + q;
      int gs = (g & ~7) | ((g & 7) ^ (row & 7));
      bf16x8 xv = *(const bf16x8*)&xbuf[row * 256 + gs * 8];
      float4 ga = *(const float4*)(g2 + ks * 32 + q * 8);
      float4 gb = *(const float4*)(g2 + ks * 32 + q * 8 + 4);
      float4 ba = *(const float4*)(bb2 + ks * 32 + q * 8);
      float4 bb = *(const float4*)(bb2 + ks * 32 + q * 8 + 4);
      bf16x8 o;
      o[0] = (short)f2bf((bf2f((u16)xv[0]) - meanK) * rstdK * ga.x + ba.x);
      o[1] = (short)f2bf((bf2f((u16)xv[1]) - meanK) * rstdK * ga.y + ba.y);
      o[2] = (short)f2bf((bf2f((u16)xv[2]) - meanK) * rstdK * ga.z + ba.z);
      o[3] = (short)f2bf((bf2f((u16)xv[3]) - meanK) * rstdK * ga.w + ba.w);
      o[4] = (short)f2bf((bf2f((u16)xv[4]) - meanK) * rstdK * gb.x + bb.x);
      o[5] = (short)f2bf((bf2f((u16)xv[5]) - meanK) * rstdK * gb.y + bb.y);
      o[6] = (short)f2bf((bf2f((u16)xv[6]) - meanK) * rstdK * gb.z + bb.z);
      o[7] = (short)f2bf((bf2f((u16)xv[7]) - meanK) * rstdK * gb.w + bb.w);
      af[ks] = o;
    }
  }

  // ======================= Phase C: MLP (R15 schedule) =====================
  f32x4 accO[16] = {};  // wave's 16 rows x 256 out cols
  u16* sl = slab[wave];

  for (int hc = 0; hc < 32; ++hc) {
    __syncthreads();   // B1(hc) staged+drained; Bd1 free (prev G2 done)
    stageB2(hc);

    // ---- G1: S1(16x32) = A @ B1^T ----
    f32x4 acc1[2] = {};
#pragma unroll
    for (int ks = 0; ks < 8; ++ks) {
      int g = ks * 4 + q;
      bf16x8 bfv[2];
#pragma unroll
      for (int nt = 0; nt < 2; ++nt) {
        int r = nt * 16 + m;
        int gs = (g & ~7) | ((g & 7) ^ (r & 7));
        bfv[nt] = *(const bf16x8*)&Bd0[r * 256 + gs * 8];
      }
#pragma unroll
      for (int nt = 0; nt < 2; ++nt)
        acc1[nt] = __builtin_amdgcn_mfma_f32_16x16x32_bf16(af[ks], bfv[nt], acc1[nt], 0, 0, 0);
    }
    // bias + gelu -> own slab
#pragma unroll
    for (int nt = 0; nt < 2; ++nt) {
      float b1 = fb1[hc * 32 + nt * 16 + m];
      int gcol = nt * 2 + (m >> 3);
#pragma unroll
      for (int r = 0; r < 4; ++r) {
        int row = q * 4 + r;
        float h = gelu_f(acc1[nt][r] + b1);
        int gs = gcol ^ ((row >> 1) & 3);
        sl[row * 32 + gs * 8 + (m & 7)] = f2bf(h);
      }
    }
    __syncthreads();   // B2(hc) staged+drained; Bd0 readers done
    if (hc + 1 < 32) stageB1(hc + 1);  // overlaps G2

    // ---- G2: accO += S1 @ B2^T ----
    {
      int gsa = q ^ ((m >> 1) & 3);
      bf16x8 pa = *(const bf16x8*)&sl[m * 32 + gsa * 8];
#pragma unroll
      for (int nt = 0; nt < 16; ++nt) {
        int n = nt * 16 + m;
        int gs2 = q ^ ((n >> 1) & 3);
        bf16x8 bv2 = *(const bf16x8*)&Bd1[n * 32 + gs2 * 8];
        accO[nt] = __builtin_amdgcn_mfma_f32_16x16x32_bf16(pa, bv2, accO[nt], 0, 0, 0);
      }
    }
  }

  // ============ Phase D: out = x + accO + fb2, scatter via winmap ==========
#pragma unroll
  for (int nt = 0; nt < 16; ++nt) {
    int col = nt * 16 + m;
    float b2 = fb2[col];
    int g = col >> 3;
#pragma unroll
    for (int r = 0; r < 4; ++r) {
      int row = wave * 16 + q * 4 + r;
      int gs = (g & ~7) | ((g & 7) ^ (row & 7));
      float xv = bf2f(xbuf[row * 256 + gs * 8 + (col & 7)]);
      out[obaseP[r] + col] = xv + accO[nt][r] + b2;
    }
  }
}

// ------------------------------------------------------- MFMA attention -----
__global__ __launch_bounds__(64)
void attn_mfma(const u16* __restrict__ q, const u16* __restrict__ k,
               const u16* __restrict__ v, const float* __restrict__ Bp,
               u16* __restrict__ out) {
  __shared__ u16 Pl[64 * 64];
  __shared__ u16 VT[32 * 64];
  const int lane = threadIdx.x;
  const int unit = blockIdx.x;
  const int win = unit >> 3, head = unit & 7;
  const size_t base = (size_t)win * 49 * 256 + head * 32;

  {
    const int key = lane;
    const u16* vp = v + base + (size_t)key * 256;
#pragma unroll
    for (int p = 0; p < 4; ++p) {
      bf16x8 vv = {};
      if (key < 49) vv = *(const bf16x8*)(vp + p * 8);
#pragma unroll
      for (int e = 0; e < 8; ++e) {
        int dim = p * 8 + e;
        int sw = (dim ^ (dim >> 3)) & 7;
        VT[dim * 64 + ((((key >> 3) ^ sw) << 3) | (key & 7))] = (u16)vv[e];
      }
    }
  }

  const f32x4* bp = (const f32x4*)(Bp + (size_t)((win & 63) * 8 + head) * 4096);
  f32x4 acc[4][4];
#pragma unroll
  for (int mi = 0; mi < 4; ++mi)
#pragma unroll
    for (int ni = 0; ni < 4; ++ni)
      acc[mi][ni] = bp[(mi * 4 + ni) * 64 + lane];

  bf16x8 qf[4], kf[4];
#pragma unroll
  for (int mi = 0; mi < 4; ++mi)
    qf[mi] = *(const bf16x8*)(q + base + (size_t)(mi * 16 + (lane & 15)) * 256 + (lane >> 4) * 8);
#pragma unroll
  for (int ni = 0; ni < 4; ++ni)
    kf[ni] = *(const bf16x8*)(k + base + (size_t)(ni * 16 + (lane & 15)) * 256 + (lane >> 4) * 8);

#pragma unroll
  for (int mi = 0; mi < 4; ++mi)
#pragma unroll
    for (int ni = 0; ni < 4; ++ni)
      acc[mi][ni] = __builtin_amdgcn_mfma_f32_16x16x32_bf16(qf[mi], kf[ni], acc[mi][ni], 0, 0, 0);

  float rinv[4][4];
#pragma unroll
  for (int mi = 0; mi < 4; ++mi) {
#pragma unroll
    for (int r = 0; r < 4; ++r) {
      float mx = fmaxf(fmaxf(acc[mi][0][r], acc[mi][1][r]),
                       fmaxf(acc[mi][2][r], acc[mi][3][r]));
#pragma unroll
      for (int off = 1; off < 16; off <<= 1) mx = fmaxf(mx, __shfl_xor(mx, off));
      float s = 0.f;
#pragma unroll
      for (int ni = 0; ni < 4; ++ni) {
        float e = __expf(acc[mi][ni][r] - mx);
        acc[mi][ni][r] = e;
        s += e;
      }
#pragma unroll
      for (int off = 1; off < 16; off <<= 1) s += __shfl_xor(s, off);
      rinv[mi][r] = 1.f / s;
    }
  }

#pragma unroll
  for (int mi = 0; mi < 4; ++mi)
#pragma unroll
    for (int ni = 0; ni < 4; ++ni)
#pragma unroll
      for (int r = 0; r < 4; ++r) {
        int row = mi * 16 + (lane >> 4) * 4 + r;
        int col = ni * 16 + (lane & 15);
        int sw = (row ^ (row >> 3)) & 7;
        Pl[row * 64 + ((((col >> 3) ^ sw) << 3) | (col & 7))] = f2bf(acc[mi][ni][r]);
      }

  f32x4 acc2[4][2] = {};
#pragma unroll
  for (int ks = 0; ks < 2; ++ks) {
    bf16x8 pa[4], vb[2];
#pragma unroll
    for (int mi = 0; mi < 4; ++mi) {
      int row = mi * 16 + (lane & 15);
      int sw = (row ^ (row >> 3)) & 7;
      pa[mi] = *(const bf16x8*)&Pl[row * 64 + (((ks * 4 + (lane >> 4)) ^ sw) << 3)];
    }
#pragma unroll
    for (int n2 = 0; n2 < 2; ++n2) {
      int dim = n2 * 16 + (lane & 15);
      int sw = (dim ^ (dim >> 3)) & 7;
      vb[n2] = *(const bf16x8*)&VT[dim * 64 + (((ks * 4 + (lane >> 4)) ^ sw) << 3)];
    }
#pragma unroll
    for (int mi = 0; mi < 4; ++mi)
#pragma unroll
      for (int n2 = 0; n2 < 2; ++n2)
        acc2[mi][n2] = __builtin_amdgcn_mfma_f32_16x16x32_bf16(pa[mi], vb[n2], acc2[mi][n2], 0, 0, 0);
  }

#pragma unroll
  for (int mi = 0; mi < 4; ++mi)
#pragma unroll
    for (int r = 0; r < 4; ++r) {
      int row = mi * 16 + (lane >> 4) * 4 + r;
      if (row < 49) {
        float rv = rinv[mi][r];
#pragma unroll
        for (int n2 = 0; n2 < 2; ++n2) {
          int col = n2 * 16 + (lane & 15);
          out[base + (size_t)row * 256 + col] = f2bf(acc2[mi][n2][r] * rv);
        }
      }
    }
}

// ---------------------------------------------------------------- launch ----
extern "C" void kernel_launch(void* const* d_in, const int* in_sizes, int n_in,
                              void* d_out, int out_size, void* d_ws, size_t ws_size,
                              hipStream_t stream) {
  const float* x1 = (const float*)d_in[0];
  const float* x2 = (const float*)d_in[1];
  const float* x3 = (const float*)d_in[2];
  const float* amask = (const float*)d_in[3];
  const float* g1 = (const float*)d_in[4];
  const float* bb1 = (const float*)d_in[5];
  const float* wq = (const float*)d_in[6];
  const float* bq = (const float*)d_in[7];
  const float* wk = (const float*)d_in[8];
  const float* bk = (const float*)d_in[9];
  const float* wv = (const float*)d_in[10];
  const float* bvb = (const float*)d_in[11];
  const float* rel = (const float*)d_in[12];
  const float* wp = (const float*)d_in[13];
  const float* bp = (const float*)d_in[14];
  const float* g2 = (const float*)d_in[15];
  const float* bb2 = (const float*)d_in[16];
  const float* fw1 = (const float*)d_in[17];
  const float* fb1 = (const float*)d_in[18];
  const float* fw2 = (const float*)d_in[19];
  const float* fb2 = (const float*)d_in[20];

  char* wsb = (char*)d_ws;
  const size_t S = (size_t)50176 * 256 * 2;  // one bf16 token-matrix slot
  u16* attn_o = (u16*)(wsb + 0 * S);
  u16* qb = (u16*)(wsb + 3 * S);             // q,k,v contiguous (QKV y-batch)
  u16* kbuf = (u16*)(wsb + 4 * S);
  u16* vbuf = (u16*)(wsb + 5 * S);
  u16* wqt = (u16*)(wsb + 6 * S);            // wqt,wkt,wvt contiguous
  u16* wkt = wqt + 65536;
  u16* wvt = wkt + 65536;
  u16* wpt = wvt + 65536;
  u16* fw1t = wpt + 65536;
  u16* fw2t = fw1t + 262144;
  float* Bp = (float*)(fw2t + 262144);       // attn bias (8.4MB)

  prep_all<<<dim3(704), 256, 0, stream>>>(wq, wk, wv, wp, fw1, fw2, wqt, wkt,
                                          wvt, wpt, fw1t, fw2t, rel, amask, Bp);

  // QKV with fused LN1+shift+window (y selects matrix; alpha on Q only)
  gemm_qkv<<<dim3(784, 3), 256, 0, stream>>>(
      x1, x2, x3, g1, bb1, wqt, bq, bk, bvb, 0.17677669529663687f, qb);

  attn_mfma<<<dim3(8192), 64, 0, stream>>>(qb, kbuf, vbuf, Bp, attn_o);

  // proj + win_rev + unshift + residual + LN2 + MLP + residual -> d_out
  proj_mlp<<<dim3(784), 256, 0, stream>>>(attn_o, wpt, bp, x1, g2, bb2,
                                          fw1t, fb1, fw2t, fb2,
                                          (float*)d_out);
}